// Round 10
// baseline (606.056 us; speedup 1.0000x reference)
//
#include <hip/hip_runtime.h>
#include <stdint.h>

#define B_ 8
#define N_ 4096
#define C_ 1024
#define H_ 16
#define M_ (B_*N_)          // 32768 rows
#define BH_ (B_*H_)         // 128

typedef unsigned short u16;
typedef unsigned int   u32;
typedef __bf16 bf16x8 __attribute__((ext_vector_type(8)));
typedef float  f32x4  __attribute__((ext_vector_type(4)));

// ---------- helpers ----------
__device__ __forceinline__ u16 f2bf(float f) {
  union { float f; u32 u; } x; x.f = f;
  u32 r = x.u + 0x7fffu + ((x.u >> 16) & 1u);   // RNE
  return (u16)(r >> 16);
}
__device__ __forceinline__ float bf2f(u16 b) {
  union { u32 u; float f; } x; x.u = ((u32)b) << 16;
  return x.f;
}
__device__ __forceinline__ void gload16(const void* g, void* l) {
  __builtin_amdgcn_global_load_lds(
      (const __attribute__((address_space(1))) void*)g,
      (__attribute__((address_space(3))) void*)l,
      16, 0, 0);
}
__device__ __forceinline__ void unpack8(uint4 r, float* f) {
  const u32 w[4] = {r.x, r.y, r.z, r.w};
#pragma unroll
  for (int i = 0; i < 4; ++i) {
    f[2*i]   = bf2f((u16)(w[i] & 0xffffu));
    f[2*i+1] = bf2f((u16)(w[i] >> 16));
  }
}
__device__ __forceinline__ uint4 pack8(const float* f) {
  uint4 r; u32* w = (u32*)&r;
#pragma unroll
  for (int i = 0; i < 4; ++i)
    w[i] = (u32)f2bf(f[2*i]) | ((u32)f2bf(f[2*i+1]) << 16);
  return r;
}
__device__ __forceinline__ bf16x8 packbf8(const float* f) {
  uint4 p = pack8(f);
  return *reinterpret_cast<bf16x8*>(&p);
}

#define BAR       __builtin_amdgcn_s_barrier()
#define LGKM(N)   asm volatile("s_waitcnt lgkmcnt(" #N ")" ::: "memory")
#define VMCNT(N)  asm volatile("s_waitcnt vmcnt(" #N ")" ::: "memory")

// ---------- 1) cast x fp32 -> bf16 ----------
__global__ void cast_f32_bf16(const float* __restrict__ in, u16* __restrict__ out, int n4) {
  int i = blockIdx.x * blockDim.x + threadIdx.x;
  const int stride = gridDim.x * blockDim.x;
  for (; i < n4; i += stride) {
    float4 v = reinterpret_cast<const float4*>(in)[i];
    u32 lo = (u32)f2bf(v.x) | ((u32)f2bf(v.y) << 16);
    u32 hi = (u32)f2bf(v.z) | ((u32)f2bf(v.w) << 16);
    uint2 o; o.x = lo; o.y = hi;
    reinterpret_cast<uint2*>(out)[i] = o;
  }
}

// ---------- 2) transpose + cast weights: [R][Cc] fp32 -> [Cc][R] bf16 ----------
__global__ void transpose_cast(const float* __restrict__ in, u16* __restrict__ out,
                               int R, int Cc) {
  __shared__ float t[32][33];
  const int bx = blockIdx.x * 32;
  const int by = blockIdx.y * 32;
  const int tx = threadIdx.x & 31;
  const int ty = threadIdx.x >> 5;
#pragma unroll
  for (int j = 0; j < 4; ++j) {
    const int r = by + ty + j * 8;
    t[ty + j * 8][tx] = in[(size_t)r * Cc + bx + tx];
  }
  __syncthreads();
#pragma unroll
  for (int j = 0; j < 4; ++j) {
    const int c = bx + ty + j * 8;
    out[(size_t)c * R + by + tx] = f2bf(t[tx][ty + j * 8]);
  }
}

// ---------- 3) 256x256 8-wave GEMM, READ-AHEAD (R3 mapping + shifted reads) --
// Reads of phase p feed MFMA of phase p+1; counted lgkm 4/8/4/8 lets the LDS
// drain overlap MFMA. Same staging slots + vmcnt(4)/tile gate as R3 (proven).
// Ledger: stage targets' readers retired >=1 barrier+wait before stage issue;
// gate retires h1 regions formally; next-tile h0 read-aheads trail their stage
// by 3-6 phases (same latency class R3 used). Tail read-aheads read stale LDS
// into dead regs (uniform lgkm counts), harmless.
template <int NC, bool OUT_BF16>
__global__ __launch_bounds__(512) void gemm256(const u16* __restrict__ A,
                                               const u16* __restrict__ Bt,
                                               const float* __restrict__ bias,
                                               void* __restrict__ outp,
                                               int K, int cpx) {
  __shared__ __align__(16) u16 As[2][256 * 64];
  __shared__ __align__(16) u16 Bs[2][256 * 64];
  const int tid  = threadIdx.x;
  const int lane = tid & 63;
  const int w    = tid >> 6;
  const int wm   = (w >> 2) & 1;
  const int wn   = w & 3;
  const int l15  = lane & 15;
  const int lk   = lane >> 4;

  const int bid = blockIdx.x;
  const int wg  = (bid & 7) * cpx + (bid >> 3);
  const size_t brow = (size_t)(wg & 127) * 256;
  const size_t bcol = (size_t)(wg >> 7) * 256;

  const int KTn = K >> 6;   // even
  f32x4 acc[2][2][4][2] = {};   // [mh][nh][mf][nf]

  auto stage = [&](const u16* __restrict__ src, size_t rowbase, int kt,
                   u16* lds_tile, int h) {
#pragma unroll
    for (int is = 0; is < 2; ++is) {
      const int lin   = is * 8192 + tid * 16;
      const int row   = lin >> 7;
      const int chunk = ((lin >> 4) & 7) ^ (row & 7);  // inverse swizzle on SOURCE
      gload16(src + (rowbase + (size_t)(h * 128 + row)) * K + kt * 64 + chunk * 8,
              (char*)lds_tile + h * 16384 + lin);
    }
  };
  auto readA = [&](bf16x8 (&d)[4][2], const u16* tb, int mh) {
#pragma unroll
    for (int mf = 0; mf < 4; ++mf)
#pragma unroll
      for (int kc = 0; kc < 2; ++kc) {
        const int row   = mh * 128 + wm * 64 + mf * 16 + l15;
        const int chunk = ((kc << 2) | lk) ^ (row & 7);
        d[mf][kc] = *reinterpret_cast<const bf16x8*>((const char*)tb + row * 128 + chunk * 16);
      }
  };
  auto readB = [&](bf16x8 (&d)[2][2], const u16* tb, int nh) {
#pragma unroll
    for (int nf = 0; nf < 2; ++nf)
#pragma unroll
      for (int kc = 0; kc < 2; ++kc) {
        const int row   = nh * 128 + wn * 32 + nf * 16 + l15;
        const int chunk = ((kc << 2) | lk) ^ (row & 7);
        d[nf][kc] = *reinterpret_cast<const bf16x8*>((const char*)tb + row * 128 + chunk * 16);
      }
  };
  auto quad = [&](bf16x8 (&af)[4][2], bf16x8 (&bf)[2][2], f32x4 (&ac)[4][2]) {
    __builtin_amdgcn_s_setprio(1);
#pragma unroll
    for (int kc = 0; kc < 2; ++kc)   // kc outer: 8 indep accs between dep pairs
#pragma unroll
      for (int mf = 0; mf < 4; ++mf)
#pragma unroll
        for (int nf = 0; nf < 2; ++nf)
          ac[mf][nf] = __builtin_amdgcn_mfma_f32_16x16x32_bf16(
              af[mf][kc], bf[nf][kc], ac[mf][nf], 0, 0, 0);
    __builtin_amdgcn_s_setprio(0);
  };

  bf16x8 a0[4][2], a1[4][2], b1[2][2], b0e[2][2], b0o[2][2];

  // prologue: tile0 all 4 halves + tile1 h0 pair; vmcnt(4) retires tile0
  stage(A,  brow, 0, As[0], 0);
  stage(Bt, bcol, 0, Bs[0], 0);
  stage(A,  brow, 0, As[0], 1);
  stage(Bt, bcol, 0, Bs[0], 1);
  stage(A,  brow, 1, As[1], 0);
  stage(Bt, bcol, 1, Bs[1], 0);
  VMCNT(4);
  BAR;
  readA(a0, As[0], 0);      // tile0 Ah0 frags
  readB(b0e, Bs[0], 0);     // tile0 Bh0 frags

  for (int tt = 0; tt < KTn; tt += 2) {
    const bool s2 = (tt + 2) < KTn;
    const bool s3 = (tt + 3) < KTn;

    // ===== tile tt (buf0; b0e current, b0o loading) =====
    // phE0: read b1(tt); stage As[1].h1<-tt+1; MFMA (0,0) a0*b0e
    readB(b1, Bs[0], 1);
    stage(A, brow, tt + 1, As[1], 1);
    BAR; LGKM(4);
    quad(a0, b0e, acc[0][0]);
    BAR;

    // phE1: read a1(tt); stage Bs[1].h1<-tt+1; MFMA (0,1) a0*b1
    readA(a1, As[0], 1);
    stage(Bt, bcol, tt + 1, Bs[1], 1);
    BAR; LGKM(8);
    quad(a0, b1, acc[0][1]);
    BAR;

    // phE2: read-ahead b0o<-Bs[1].h0 (tile tt+1); stage As[0].h0<-tt+2;
    //       MFMA (1,1) a1*b1
    readB(b0o, Bs[1], 0);
    if (s2) stage(A, brow, tt + 2, As[0], 0);
    BAR; LGKM(4);
    quad(a1, b1, acc[1][1]);
    BAR;

    // phE3: read-ahead a0<-As[1].h0 (tile tt+1); stage Bs[0].h0<-tt+2; GATE;
    //       MFMA (1,0) a1*b0e
    readA(a0, As[1], 0);
    if (s2) { stage(Bt, bcol, tt + 2, Bs[0], 0); VMCNT(4); }
    else    { VMCNT(0); }
    BAR; LGKM(8);
    quad(a1, b0e, acc[1][0]);
    BAR;

    // ===== tile tt+1 (buf1; b0o current, b0e loading) =====
    // phO0: read b1(tt+1); stage As[0].h1<-tt+2; MFMA (0,0) a0*b0o
    readB(b1, Bs[1], 1);
    if (s2) stage(A, brow, tt + 2, As[0], 1);
    BAR; LGKM(4);
    quad(a0, b0o, acc[0][0]);
    BAR;

    // phO1: read a1(tt+1); stage Bs[0].h1<-tt+2; MFMA (0,1) a0*b1
    readA(a1, As[1], 1);
    if (s2) stage(Bt, bcol, tt + 2, Bs[0], 1);
    BAR; LGKM(8);
    quad(a0, b1, acc[0][1]);
    BAR;

    // phO2: read-ahead b0e<-Bs[0].h0 (tile tt+2); stage As[1].h0<-tt+3;
    //       MFMA (1,1) a1*b1
    readB(b0e, Bs[0], 0);
    if (s3) stage(A, brow, tt + 3, As[1], 0);
    BAR; LGKM(4);
    quad(a1, b1, acc[1][1]);
    BAR;

    // phO3: read-ahead a0<-As[0].h0 (tile tt+2); stage Bs[1].h0<-tt+3; GATE;
    //       MFMA (1,0) a1*b0o
    readA(a0, As[0], 0);
    if (s3) { stage(Bt, bcol, tt + 3, Bs[1], 0); VMCNT(4); }
    else    { VMCNT(0); }
    BAR; LGKM(8);
    quad(a1, b0o, acc[1][0]);
    BAR;
  }

  // epilogue: C/D layout col=lane&15, row=(lane>>4)*4+reg  [m89-verified]
#pragma unroll
  for (int mh = 0; mh < 2; ++mh)
#pragma unroll
  for (int nh = 0; nh < 2; ++nh)
#pragma unroll
  for (int mf = 0; mf < 4; ++mf)
#pragma unroll
  for (int nf = 0; nf < 2; ++nf) {
    const size_t col = bcol + nh * 128 + wn * 32 + nf * 16 + l15;
    const float bv = bias[col];
    const size_t row0 = brow + mh * 128 + wm * 64 + mf * 16 + lk * 4;
#pragma unroll
    for (int r = 0; r < 4; ++r) {
      const float v = acc[mh][nh][mf][nf][r] + bv;
      if constexpr (OUT_BF16)
        ((u16*)outp)[(row0 + r) * NC + col] = f2bf(v);
      else
        ((float*)outp)[(row0 + r) * NC + col] = v;
    }
  }
}

// ---------- 4) qsc: per-(row,h) q scale = 1/max(||q||,eps) ----------
__global__ void qsc_kernel(const u16* __restrict__ qkv, float* __restrict__ qsc) {
  const int t = threadIdx.x;
  const size_t p = (size_t)blockIdx.x * 32 + (t >> 3);   // (row,h) pair
  const int c8 = t & 7;
  const size_t row = p >> 4;
  const int h = (int)(p & 15);
  uint4 raw = *reinterpret_cast<const uint4*>(qkv + row * 3072 + h * 64 + c8 * 8);
  float f[8]; unpack8(raw, f);
  float ss = 0.f;
#pragma unroll
  for (int j = 0; j < 8; ++j) ss += f[j] * f[j];
  ss += __shfl_xor(ss, 1); ss += __shfl_xor(ss, 2); ss += __shfl_xor(ss, 4);
  if (c8 == 0) qsc[p] = 1.f / fmaxf(sqrtf(ss), 1e-12f);
}

// ---------- 5) kv_fused: part[sp][bh][e][d] = sum_n v[n][e]*k_norm[n][d] ----
__global__ __launch_bounds__(256) void kv_fused(const u16* __restrict__ qkv,
                                                float* __restrict__ part) {
  const int bh = blockIdx.x, sp = blockIdx.y;
  const int b = bh >> 4, h = bh & 15;
  const int tid  = threadIdx.x;
  const int lane = tid & 63;
  const int w    = tid >> 6;
  const int wm   = w >> 1, wn = w & 1;
  const int l15  = lane & 15;
  const int lk   = lane >> 4;

  __shared__ float Ks[64 * 65];
  __shared__ float Vs[64 * 65];

  f32x4 acc[2][2] = {};
  const size_t nbase = (size_t)b * N_ + (size_t)sp * 512;

  for (int ch = 0; ch < 8; ++ch) {
    __syncthreads();
#pragma unroll
    for (int it = 0; it < 2; ++it) {
      const int idx = it * 256 + tid;
      const int r = idx >> 3, c8 = idx & 7;
      const size_t rowoff = (nbase + (size_t)(ch * 64 + r)) * 3072 + h * 64 + c8 * 8;
      uint4 kraw = *reinterpret_cast<const uint4*>(qkv + rowoff + 1024);
      float kf[8]; unpack8(kraw, kf);
      float ss = 0.f;
#pragma unroll
      for (int j = 0; j < 8; ++j) ss += kf[j] * kf[j];
      ss += __shfl_xor(ss, 1); ss += __shfl_xor(ss, 2); ss += __shfl_xor(ss, 4);
      const float sc = 1.f / fmaxf(sqrtf(ss), 1e-12f);
#pragma unroll
      for (int j = 0; j < 8; ++j) Ks[r * 65 + c8 * 8 + j] = kf[j] * sc;
      uint4 vraw = *reinterpret_cast<const uint4*>(qkv + rowoff + 2048);
      float vf[8]; unpack8(vraw, vf);
#pragma unroll
      for (int j = 0; j < 8; ++j) Vs[r * 65 + c8 * 8 + j] = vf[j];
    }
    __syncthreads();

    bf16x8 fa[2][2], fb[2][2];
#pragma unroll
    for (int mf = 0; mf < 2; ++mf)
#pragma unroll
      for (int kc = 0; kc < 2; ++kc) {
        const int e = wm * 32 + mf * 16 + l15;
        float tmp[8];
#pragma unroll
        for (int j = 0; j < 8; ++j) tmp[j] = Vs[(kc * 32 + lk * 8 + j) * 65 + e];
        fa[mf][kc] = packbf8(tmp);
      }
#pragma unroll
    for (int nf = 0; nf < 2; ++nf)
#pragma unroll
      for (int kc = 0; kc < 2; ++kc) {
        const int d = wn * 32 + nf * 16 + l15;
        float tmp[8];
#pragma unroll
        for (int j = 0; j < 8; ++j) tmp[j] = Ks[(kc * 32 + lk * 8 + j) * 65 + d];
        fb[nf][kc] = packbf8(tmp);
      }
#pragma unroll
    for (int mf = 0; mf < 2; ++mf)
#pragma unroll
      for (int nf = 0; nf < 2; ++nf)
#pragma unroll
        for (int kc = 0; kc < 2; ++kc)
          acc[mf][nf] = __builtin_amdgcn_mfma_f32_16x16x32_bf16(
              fa[mf][kc], fb[nf][kc], acc[mf][nf], 0, 0, 0);
  }

  float* base = part + ((size_t)sp * BH_ + bh) * 4096;
#pragma unroll
  for (int mf = 0; mf < 2; ++mf)
#pragma unroll
    for (int nf = 0; nf < 2; ++nf)
#pragma unroll
      for (int r = 0; r < 4; ++r) {
        const int e = wm * 32 + mf * 16 + lk * 4 + r;
        const int d = wn * 32 + nf * 16 + l15;
        base[e * 64 + d] = acc[mf][nf][r];
      }
}

// ---------- 6) reduce 8 kv partials -> kvT bf16 ----------
__global__ void kv_reduce8(const float* __restrict__ part, u16* __restrict__ kvT) {
  const int i4 = (blockIdx.x * 256 + threadIdx.x) * 4;
  float4 s = *reinterpret_cast<const float4*>(part + i4);
#pragma unroll
  for (int sp = 1; sp < 8; ++sp) {
    float4 p = *reinterpret_cast<const float4*>(part + (size_t)sp * 524288 + i4);
    s.x += p.x; s.y += p.y; s.z += p.z; s.w += p.w;
  }
  u32 lo = (u32)f2bf(s.x) | ((u32)f2bf(s.y) << 16);
  u32 hi = (u32)f2bf(s.z) | ((u32)f2bf(s.w) << 16);
  uint2 o; o.x = lo; o.y = hi;
  *reinterpret_cast<uint2*>(kvT + i4) = o;
}

// ---------- 7) attn_gemm: attn = (q @ kv) * qsc ----------
__global__ void attn_gemm(const u16* __restrict__ qkv, const u16* __restrict__ kvT,
                          const float* __restrict__ qsc, u16* __restrict__ attn) {
  const int bh = blockIdx.x, nt = blockIdx.y;
  const int b = bh >> 4, h = bh & 15;
  const int n0 = nt * 128;
  __shared__ __align__(16) u16 Qs[128 * 64];
  __shared__ __align__(16) u16 Ks[64 * 64];
  const int tid  = threadIdx.x;
  const int lane = tid & 63;
  const int wm   = tid >> 6;
  const int l15  = lane & 15;
  const int lk   = lane >> 4;

#pragma unroll
  for (int is = 0; is < 4; ++is) {
    const int lin   = is * 4096 + tid * 16;
    const int row   = lin >> 7;
    const int chunk = ((lin >> 4) & 7) ^ (row & 7);
    gload16(qkv + ((size_t)(b * N_ + n0 + row)) * 3072 + h * 64 + chunk * 8,
            (char*)Qs + lin);
  }
#pragma unroll
  for (int is = 0; is < 2; ++is) {
    const int lin   = is * 4096 + tid * 16;
    const int row   = lin >> 7;
    const int chunk = ((lin >> 4) & 7) ^ (row & 7);
    gload16(kvT + (size_t)bh * 4096 + row * 64 + chunk * 8, (char*)Ks + lin);
  }
  __syncthreads();

  bf16x8 fq[2][2], fk[4][2];
#pragma unroll
  for (int mf = 0; mf < 2; ++mf)
#pragma unroll
    for (int kc = 0; kc < 2; ++kc) {
      const int row = wm * 32 + mf * 16 + l15;
      const int chunk = ((kc << 2) | lk) ^ (row & 7);
      fq[mf][kc] = *reinterpret_cast<const bf16x8*>((const char*)Qs + row * 128 + chunk * 16);
    }
#pragma unroll
  for (int nf = 0; nf < 4; ++nf)
#pragma unroll
    for (int kc = 0; kc < 2; ++kc) {
      const int row = nf * 16 + l15;
      const int chunk = ((kc << 2) | lk) ^ (row & 7);
      fk[nf][kc] = *reinterpret_cast<const bf16x8*>((const char*)Ks + row * 128 + chunk * 16);
    }
  f32x4 acc[2][4] = {};
#pragma unroll
  for (int mf = 0; mf < 2; ++mf)
#pragma unroll
    for (int nf = 0; nf < 4; ++nf)
#pragma unroll
      for (int kc = 0; kc < 2; ++kc)
        acc[mf][nf] = __builtin_amdgcn_mfma_f32_16x16x32_bf16(
            fq[mf][kc], fk[nf][kc], acc[mf][nf], 0, 0, 0);

#pragma unroll
  for (int mf = 0; mf < 2; ++mf)
#pragma unroll
    for (int r = 0; r < 4; ++r) {
      const size_t row = (size_t)(b * N_ + n0 + wm * 32 + mf * 16 + lk * 4 + r);
      const float sc = qsc[row * 16 + h];
#pragma unroll
      for (int nf = 0; nf < 4; ++nf)
        attn[row * 1024 + h * 64 + nf * 16 + l15] = f2bf(acc[mf][nf][r] * sc);
    }
}

// ---------- workspace layout (bytes) ----------
#define WS_XB     0ull            // bf16 xb [32768][1024] (dead after QKV gemm)
#define WS_QKV    67108864ull     // bf16 [32768][3072] (q stays raw)
#define WS_VT     268435456ull    // part f32 [8][128][4096]=16MB, THEN attn bf16 64MB
#define WS_WQKV   335544320ull    // bf16 [3072][1024]
#define WS_WPROJ  341835776ull    // bf16 [1024][1024]
#define WS_QSC    343932928ull    // f32  [32768][16] = 2MB
#define WS_KVT    360710144ull    // bf16 [128][64][64] = 1MB

extern "C" void kernel_launch(void* const* d_in, const int* in_sizes, int n_in,
                              void* d_out, int out_size, void* d_ws, size_t ws_size,
                              hipStream_t stream) {
  const float* x      = (const float*)d_in[0];
  const float* qkv_w  = (const float*)d_in[1];
  const float* qkv_b  = (const float*)d_in[2];
  const float* proj_w = (const float*)d_in[3];
  const float* proj_b = (const float*)d_in[4];

  char* ws = (char*)d_ws;
  u16*   xb      = (u16*)(ws + WS_XB);
  u16*   qkv     = (u16*)(ws + WS_QKV);
  float* part    = (float*)(ws + WS_VT);
  u16*   attn    = (u16*)(ws + WS_VT);
  u16*   wqkv_t  = (u16*)(ws + WS_WQKV);
  u16*   wproj_t = (u16*)(ws + WS_WPROJ);
  float* qsc     = (float*)(ws + WS_QSC);
  u16*   kvT     = (u16*)(ws + WS_KVT);

  cast_f32_bf16<<<2048, 256, 0, stream>>>(x, xb, (M_ * C_) / 4);
  transpose_cast<<<dim3(96, 32), 256, 0, stream>>>(qkv_w, wqkv_t, 1024, 3072);
  transpose_cast<<<dim3(32, 32), 256, 0, stream>>>(proj_w, wproj_t, 1024, 1024);
  gemm256<3072, true><<<1536, 512, 0, stream>>>(xb, wqkv_t, qkv_b, qkv, 1024, 192);
  qsc_kernel<<<16384, 256, 0, stream>>>(qkv, qsc);
  kv_fused<<<dim3(128, 8), 256, 0, stream>>>(qkv, part);
  kv_reduce8<<<512, 256, 0, stream>>>(part, kvT);
  attn_gemm<<<dim3(128, 32), 256, 0, stream>>>(qkv, kvT, qsc, attn);
  gemm256<1024, false><<<512, 512, 0, stream>>>(attn, wproj_t, proj_b, d_out, 1024, 64);
}

// Round 11
// 421.601 us; speedup vs baseline: 1.4375x; 1.4375x over previous
//
#include <hip/hip_runtime.h>
#include <stdint.h>

#define B_ 8
#define N_ 4096
#define C_ 1024
#define H_ 16
#define M_ (B_*N_)          // 32768 rows
#define BH_ (B_*H_)         // 128

typedef unsigned short u16;
typedef unsigned int   u32;
typedef __bf16 bf16x8 __attribute__((ext_vector_type(8)));
typedef float  f32x4  __attribute__((ext_vector_type(4)));

// ---------- helpers ----------
__device__ __forceinline__ u16 f2bf(float f) {
  union { float f; u32 u; } x; x.f = f;
  u32 r = x.u + 0x7fffu + ((x.u >> 16) & 1u);   // RNE
  return (u16)(r >> 16);
}
__device__ __forceinline__ float bf2f(u16 b) {
  union { u32 u; float f; } x; x.u = ((u32)b) << 16;
  return x.f;
}
__device__ __forceinline__ void gload16(const void* g, void* l) {
  __builtin_amdgcn_global_load_lds(
      (const __attribute__((address_space(1))) void*)g,
      (__attribute__((address_space(3))) void*)l,
      16, 0, 0);
}
__device__ __forceinline__ void unpack8(uint4 r, float* f) {
  const u32 w[4] = {r.x, r.y, r.z, r.w};
#pragma unroll
  for (int i = 0; i < 4; ++i) {
    f[2*i]   = bf2f((u16)(w[i] & 0xffffu));
    f[2*i+1] = bf2f((u16)(w[i] >> 16));
  }
}
__device__ __forceinline__ uint4 pack8(const float* f) {
  uint4 r; u32* w = (u32*)&r;
#pragma unroll
  for (int i = 0; i < 4; ++i)
    w[i] = (u32)f2bf(f[2*i]) | ((u32)f2bf(f[2*i+1]) << 16);
  return r;
}
__device__ __forceinline__ bf16x8 packbf8(const float* f) {
  uint4 p = pack8(f);
  return *reinterpret_cast<bf16x8*>(&p);
}

// ---------- 1) cast x fp32 -> bf16 ----------
__global__ void cast_f32_bf16(const float* __restrict__ in, u16* __restrict__ out, int n4) {
  int i = blockIdx.x * blockDim.x + threadIdx.x;
  const int stride = gridDim.x * blockDim.x;
  for (; i < n4; i += stride) {
    float4 v = reinterpret_cast<const float4*>(in)[i];
    u32 lo = (u32)f2bf(v.x) | ((u32)f2bf(v.y) << 16);
    u32 hi = (u32)f2bf(v.z) | ((u32)f2bf(v.w) << 16);
    uint2 o; o.x = lo; o.y = hi;
    reinterpret_cast<uint2*>(out)[i] = o;
  }
}

// ---------- 2) transpose + cast weights: [R][Cc] fp32 -> [Cc][R] bf16 ----------
__global__ void transpose_cast(const float* __restrict__ in, u16* __restrict__ out,
                               int R, int Cc) {
  __shared__ float t[32][33];
  const int bx = blockIdx.x * 32;
  const int by = blockIdx.y * 32;
  const int tx = threadIdx.x & 31;
  const int ty = threadIdx.x >> 5;
#pragma unroll
  for (int j = 0; j < 4; ++j) {
    const int r = by + ty + j * 8;
    t[ty + j * 8][tx] = in[(size_t)r * Cc + bx + tx];
  }
  __syncthreads();
#pragma unroll
  for (int j = 0; j < 4; ++j) {
    const int c = bx + ty + j * 8;
    out[(size_t)c * R + by + tx] = f2bf(t[tx][ty + j * 8]);
  }
}

// ---------- 3) 256x256 8-wave GEMM — R3 structure (frozen; best measured) ----
// Block ordering: col-tile fastest in groups of 4 within each XCD chunk so
// co-resident blocks share an A row-panel (~4MB A + 2MB B ~= L2 per XCD).
template <int NC, bool OUT_BF16>
__global__ __launch_bounds__(512) void gemm256(const u16* __restrict__ A,
                                               const u16* __restrict__ Bt,
                                               const float* __restrict__ bias,
                                               void* __restrict__ outp,
                                               int K, int cpx) {
  __shared__ __align__(16) u16 As[2][256][64];   // 64 KB
  __shared__ __align__(16) u16 Bs[2][256][64];   // 64 KB
  const int tid  = threadIdx.x;
  const int lane = tid & 63;
  const int w    = tid >> 6;
  const int wm   = (w >> 2) & 1;
  const int wn   = w & 3;
  const int l15  = lane & 15;
  const int lk   = lane >> 4;

  const int bid = blockIdx.x;
  const int wg  = (bid & 7) * cpx + (bid >> 3);
  // col fastest (mod 4), then row-tile, then col-group (L2-friendly)
  const int col = ((wg >> 9) << 2) | (wg & 3);
  const size_t brow = (size_t)((wg >> 2) & 127) * 256;
  const size_t bcol = (size_t)col * 256;

  const int KT = K >> 6;
  f32x4 acc[2][2][4][2] = {};   // [mh][nh][mf][nf]

  auto stage = [&](const u16* __restrict__ src, size_t rowbase, int kt,
                   u16* lds_tile, int h) {
#pragma unroll
    for (int is = 0; is < 2; ++is) {
      const int lin   = is * 8192 + tid * 16;
      const int row   = lin >> 7;
      const int chunk = ((lin >> 4) & 7) ^ (row & 7);
      gload16(src + (rowbase + (size_t)(h * 128 + row)) * K + kt * 64 + chunk * 8,
              (char*)lds_tile + h * 16384 + lin);
    }
  };
  auto fragA = [&](const u16* tb, int mh, int mf, int kc) -> bf16x8 {
    const int row   = mh * 128 + wm * 64 + mf * 16 + l15;
    const int chunk = ((kc << 2) | lk) ^ (row & 7);
    return *reinterpret_cast<const bf16x8*>((const char*)tb + row * 128 + chunk * 16);
  };
  auto fragB = [&](const u16* tb, int nh, int nf, int kc) -> bf16x8 {
    const int row   = nh * 128 + wn * 32 + nf * 16 + l15;
    const int chunk = ((kc << 2) | lk) ^ (row & 7);
    return *reinterpret_cast<const bf16x8*>((const char*)tb + row * 128 + chunk * 16);
  };

#define MFMA_Q(AF, BF, MH, NH) do {                                            \
    __builtin_amdgcn_s_barrier();                                              \
    asm volatile("s_waitcnt lgkmcnt(0)" ::: "memory");                         \
    __builtin_amdgcn_s_setprio(1);                                             \
    _Pragma("unroll") for (int mf = 0; mf < 4; ++mf)                           \
      _Pragma("unroll") for (int nf = 0; nf < 2; ++nf)                         \
        _Pragma("unroll") for (int kc = 0; kc < 2; ++kc)                       \
          acc[MH][NH][mf][nf] = __builtin_amdgcn_mfma_f32_16x16x32_bf16(       \
              AF[mf][kc], BF[nf][kc], acc[MH][NH][mf][nf], 0, 0, 0);           \
    __builtin_amdgcn_s_setprio(0);                                             \
    __builtin_amdgcn_s_barrier();                                              \
  } while (0)

  // prologue: tile0 fully + tile1 Ah0/Bh0 (12 loads); vmcnt(4) -> tile0 done
  stage(A,  brow, 0, &As[0][0][0], 0);
  stage(Bt, bcol, 0, &Bs[0][0][0], 0);
  stage(A,  brow, 0, &As[0][0][0], 1);
  stage(Bt, bcol, 0, &Bs[0][0][0], 1);
  stage(A,  brow, 1, &As[1][0][0], 0);
  stage(Bt, bcol, 1, &Bs[1][0][0], 0);
  asm volatile("s_waitcnt vmcnt(4)" ::: "memory");
  __builtin_amdgcn_s_barrier();

  for (int t = 0; t < KT; ++t) {
    const u16* curA = &As[t & 1][0][0];
    const u16* curB = &Bs[t & 1][0][0];
    u16* nA  = &As[(t + 1) & 1][0][0];
    u16* nB  = &Bs[(t + 1) & 1][0][0];
    u16* n2A = &As[t & 1][0][0];
    u16* n2B = &Bs[t & 1][0][0];
    const bool s1 = (t + 1) < KT;
    const bool s2 = (t + 2) < KT;

    bf16x8 afA[4][2], afB[4][2], bf0[2][2], bf1[2][2];

    // ph0: (0,0)
#pragma unroll
    for (int mf = 0; mf < 4; ++mf)
#pragma unroll
      for (int kc = 0; kc < 2; ++kc) afA[mf][kc] = fragA(curA, 0, mf, kc);
#pragma unroll
    for (int nf = 0; nf < 2; ++nf)
#pragma unroll
      for (int kc = 0; kc < 2; ++kc) bf0[nf][kc] = fragB(curB, 0, nf, kc);
    if (s1) stage(A, brow, t + 1, nA, 1);
    MFMA_Q(afA, bf0, 0, 0);

    // ph1: (0,1)
#pragma unroll
    for (int nf = 0; nf < 2; ++nf)
#pragma unroll
      for (int kc = 0; kc < 2; ++kc) bf1[nf][kc] = fragB(curB, 1, nf, kc);
    if (s1) stage(Bt, bcol, t + 1, nB, 1);
    MFMA_Q(afA, bf1, 0, 1);

    // ph2: (1,1)
#pragma unroll
    for (int mf = 0; mf < 4; ++mf)
#pragma unroll
      for (int kc = 0; kc < 2; ++kc) afB[mf][kc] = fragA(curA, 1, mf, kc);
    if (s2) stage(A, brow, t + 2, n2A, 0);
    MFMA_Q(afB, bf1, 1, 1);

    // ph3: (1,0)
    if (s2) {
      stage(Bt, bcol, t + 2, n2B, 0);
      asm volatile("s_waitcnt vmcnt(4)" ::: "memory");
    } else {
      asm volatile("s_waitcnt vmcnt(0)" ::: "memory");
    }
    MFMA_Q(afB, bf0, 1, 0);
  }
#undef MFMA_Q

  // epilogue: C/D layout col=lane&15, row=(lane>>4)*4+reg
#pragma unroll
  for (int mh = 0; mh < 2; ++mh)
#pragma unroll
  for (int nh = 0; nh < 2; ++nh)
#pragma unroll
  for (int mf = 0; mf < 4; ++mf)
#pragma unroll
  for (int nf = 0; nf < 2; ++nf) {
    const size_t ocol = bcol + nh * 128 + wn * 32 + nf * 16 + l15;
    const float bv = bias[ocol];
    const size_t row0 = brow + mh * 128 + wm * 64 + mf * 16 + lk * 4;
#pragma unroll
    for (int r = 0; r < 4; ++r) {
      const float v = acc[mh][nh][mf][nf][r] + bv;
      if constexpr (OUT_BF16)
        ((u16*)outp)[(row0 + r) * NC + ocol] = f2bf(v);
      else
        ((float*)outp)[(row0 + r) * NC + ocol] = v;
    }
  }
}

// ---------- 4) kv_fused: part[sp][bh][e][d] = sum_n v[n][e]*k_norm[n][d] ----
__global__ __launch_bounds__(256) void kv_fused(const u16* __restrict__ qkv,
                                                float* __restrict__ part) {
  const int bh = blockIdx.x, sp = blockIdx.y;
  const int b = bh >> 4, h = bh & 15;
  const int tid  = threadIdx.x;
  const int lane = tid & 63;
  const int w    = tid >> 6;
  const int wm   = w >> 1, wn = w & 1;
  const int l15  = lane & 15;
  const int lk   = lane >> 4;

  __shared__ float Ks[64 * 65];
  __shared__ float Vs[64 * 65];

  f32x4 acc[2][2] = {};
  const size_t nbase = (size_t)b * N_ + (size_t)sp * 512;

  for (int ch = 0; ch < 8; ++ch) {
    __syncthreads();
#pragma unroll
    for (int it = 0; it < 2; ++it) {
      const int idx = it * 256 + tid;
      const int r = idx >> 3, c8 = idx & 7;
      const size_t rowoff = (nbase + (size_t)(ch * 64 + r)) * 3072 + h * 64 + c8 * 8;
      uint4 kraw = *reinterpret_cast<const uint4*>(qkv + rowoff + 1024);
      float kf[8]; unpack8(kraw, kf);
      float ss = 0.f;
#pragma unroll
      for (int j = 0; j < 8; ++j) ss += kf[j] * kf[j];
      ss += __shfl_xor(ss, 1); ss += __shfl_xor(ss, 2); ss += __shfl_xor(ss, 4);
      const float sc = 1.f / fmaxf(sqrtf(ss), 1e-12f);
#pragma unroll
      for (int j = 0; j < 8; ++j) Ks[r * 65 + c8 * 8 + j] = kf[j] * sc;
      uint4 vraw = *reinterpret_cast<const uint4*>(qkv + rowoff + 2048);
      float vf[8]; unpack8(vraw, vf);
#pragma unroll
      for (int j = 0; j < 8; ++j) Vs[r * 65 + c8 * 8 + j] = vf[j];
    }
    __syncthreads();

    bf16x8 fa[2][2], fb[2][2];
#pragma unroll
    for (int mf = 0; mf < 2; ++mf)
#pragma unroll
      for (int kc = 0; kc < 2; ++kc) {
        const int e = wm * 32 + mf * 16 + l15;
        float tmp[8];
#pragma unroll
        for (int j = 0; j < 8; ++j) tmp[j] = Vs[(kc * 32 + lk * 8 + j) * 65 + e];
        fa[mf][kc] = packbf8(tmp);
      }
#pragma unroll
    for (int nf = 0; nf < 2; ++nf)
#pragma unroll
      for (int kc = 0; kc < 2; ++kc) {
        const int d = wn * 32 + nf * 16 + l15;
        float tmp[8];
#pragma unroll
        for (int j = 0; j < 8; ++j) tmp[j] = Ks[(kc * 32 + lk * 8 + j) * 65 + d];
        fb[nf][kc] = packbf8(tmp);
      }
#pragma unroll
    for (int mf = 0; mf < 2; ++mf)
#pragma unroll
      for (int nf = 0; nf < 2; ++nf)
#pragma unroll
        for (int kc = 0; kc < 2; ++kc)
          acc[mf][nf] = __builtin_amdgcn_mfma_f32_16x16x32_bf16(
              fa[mf][kc], fb[nf][kc], acc[mf][nf], 0, 0, 0);
  }

  float* base = part + ((size_t)sp * BH_ + bh) * 4096;
#pragma unroll
  for (int mf = 0; mf < 2; ++mf)
#pragma unroll
    for (int nf = 0; nf < 2; ++nf)
#pragma unroll
      for (int r = 0; r < 4; ++r) {
        const int e = wm * 32 + mf * 16 + lk * 4 + r;
        const int d = wn * 32 + nf * 16 + l15;
        base[e * 64 + d] = acc[mf][nf][r];
      }
}

// ---------- 5) reduce 8 kv partials -> kvT bf16 ----------
__global__ void kv_reduce8(const float* __restrict__ part, u16* __restrict__ kvT) {
  const int i4 = (blockIdx.x * 256 + threadIdx.x) * 4;
  float4 s = *reinterpret_cast<const float4*>(part + i4);
#pragma unroll
  for (int sp = 1; sp < 8; ++sp) {
    float4 p = *reinterpret_cast<const float4*>(part + (size_t)sp * 524288 + i4);
    s.x += p.x; s.y += p.y; s.z += p.z; s.w += p.w;
  }
  u32 lo = (u32)f2bf(s.x) | ((u32)f2bf(s.y) << 16);
  u32 hi = (u32)f2bf(s.z) | ((u32)f2bf(s.w) << 16);
  uint2 o; o.x = lo; o.y = hi;
  *reinterpret_cast<uint2*>(kvT + i4) = o;
}

// ---------- 6) attn_gemm: attn = (q @ kv) / ||q||, norm fused in-kernel ------
__global__ void attn_gemm(const u16* __restrict__ qkv, const u16* __restrict__ kvT,
                          u16* __restrict__ attn) {
  const int bh = blockIdx.x, nt = blockIdx.y;
  const int b = bh >> 4, h = bh & 15;
  const int n0 = nt * 128;
  __shared__ __align__(16) u16 Qs[128 * 64];
  __shared__ __align__(16) u16 Ks[64 * 64];
  __shared__ float qsl[128];
  const int tid  = threadIdx.x;
  const int lane = tid & 63;
  const int wm   = tid >> 6;
  const int l15  = lane & 15;
  const int lk   = lane >> 4;

#pragma unroll
  for (int is = 0; is < 4; ++is) {
    const int lin   = is * 4096 + tid * 16;
    const int row   = lin >> 7;
    const int chunk = ((lin >> 4) & 7) ^ (row & 7);
    gload16(qkv + ((size_t)(b * N_ + n0 + row)) * 3072 + h * 64 + chunk * 8,
            (char*)Qs + lin);
  }
#pragma unroll
  for (int is = 0; is < 2; ++is) {
    const int lin   = is * 4096 + tid * 16;
    const int row   = lin >> 7;
    const int chunk = ((lin >> 4) & 7) ^ (row & 7);
    gload16(kvT + (size_t)bh * 4096 + row * 64 + chunk * 8, (char*)Ks + lin);
  }
  __syncthreads();

  // q-norm scales from the staged rows (swizzle permutes chunks within a row;
  // irrelevant for a sum). Chunk stagger -> ~4-way bank alias, not 32-way.
  if (tid < 128) {
    float ss = 0.f;
#pragma unroll
    for (int c = 0; c < 8; ++c) {
      const int ch = (c + tid) & 7;
      uint4 raw = *reinterpret_cast<const uint4*>((const char*)Qs + tid * 128 + ch * 16);
      float f[8]; unpack8(raw, f);
#pragma unroll
      for (int j = 0; j < 8; ++j) ss += f[j] * f[j];
    }
    qsl[tid] = 1.f / fmaxf(sqrtf(ss), 1e-12f);
  }
  __syncthreads();

  bf16x8 fq[2][2], fk[4][2];
#pragma unroll
  for (int mf = 0; mf < 2; ++mf)
#pragma unroll
    for (int kc = 0; kc < 2; ++kc) {
      const int row = wm * 32 + mf * 16 + l15;
      const int chunk = ((kc << 2) | lk) ^ (row & 7);
      fq[mf][kc] = *reinterpret_cast<const bf16x8*>((const char*)Qs + row * 128 + chunk * 16);
    }
#pragma unroll
  for (int nf = 0; nf < 4; ++nf)
#pragma unroll
    for (int kc = 0; kc < 2; ++kc) {
      const int row = nf * 16 + l15;
      const int chunk = ((kc << 2) | lk) ^ (row & 7);
      fk[nf][kc] = *reinterpret_cast<const bf16x8*>((const char*)Ks + row * 128 + chunk * 16);
    }
  f32x4 acc[2][4] = {};
#pragma unroll
  for (int mf = 0; mf < 2; ++mf)
#pragma unroll
    for (int nf = 0; nf < 4; ++nf)
#pragma unroll
      for (int kc = 0; kc < 2; ++kc)
        acc[mf][nf] = __builtin_amdgcn_mfma_f32_16x16x32_bf16(
            fq[mf][kc], fk[nf][kc], acc[mf][nf], 0, 0, 0);

#pragma unroll
  for (int mf = 0; mf < 2; ++mf)
#pragma unroll
    for (int r = 0; r < 4; ++r) {
      const int rloc = wm * 32 + mf * 16 + lk * 4 + r;
      const size_t row = (size_t)(b * N_ + n0 + rloc);
      const float sc = qsl[rloc];
#pragma unroll
      for (int nf = 0; nf < 4; ++nf)
        attn[row * 1024 + h * 64 + nf * 16 + l15] = f2bf(acc[mf][nf][r] * sc);
    }
}

// ---------- workspace layout (bytes) ----------
#define WS_XB     0ull            // bf16 xb [32768][1024] (dead after QKV gemm)
#define WS_QKV    67108864ull     // bf16 [32768][3072] (q stays raw)
#define WS_VT     268435456ull    // part f32 [8][128][4096]=16MB, THEN attn bf16 64MB
#define WS_WQKV   335544320ull    // bf16 [3072][1024]
#define WS_WPROJ  341835776ull    // bf16 [1024][1024]
#define WS_KVT    360710144ull    // bf16 [128][64][64] = 1MB

extern "C" void kernel_launch(void* const* d_in, const int* in_sizes, int n_in,
                              void* d_out, int out_size, void* d_ws, size_t ws_size,
                              hipStream_t stream) {
  const float* x      = (const float*)d_in[0];
  const float* qkv_w  = (const float*)d_in[1];
  const float* qkv_b  = (const float*)d_in[2];
  const float* proj_w = (const float*)d_in[3];
  const float* proj_b = (const float*)d_in[4];

  char* ws = (char*)d_ws;
  u16*   xb      = (u16*)(ws + WS_XB);
  u16*   qkv     = (u16*)(ws + WS_QKV);
  float* part    = (float*)(ws + WS_VT);
  u16*   attn    = (u16*)(ws + WS_VT);
  u16*   wqkv_t  = (u16*)(ws + WS_WQKV);
  u16*   wproj_t = (u16*)(ws + WS_WPROJ);
  u16*   kvT     = (u16*)(ws + WS_KVT);

  cast_f32_bf16<<<2048, 256, 0, stream>>>(x, xb, (M_ * C_) / 4);
  transpose_cast<<<dim3(96, 32), 256, 0, stream>>>(qkv_w, wqkv_t, 1024, 3072);
  transpose_cast<<<dim3(32, 32), 256, 0, stream>>>(proj_w, wproj_t, 1024, 1024);
  gemm256<3072, true><<<1536, 512, 0, stream>>>(xb, wqkv_t, qkv_b, qkv, 1024, 192);
  kv_fused<<<dim3(128, 8), 256, 0, stream>>>(qkv, part);
  kv_reduce8<<<512, 256, 0, stream>>>(part, kvT);
  attn_gemm<<<dim3(128, 32), 256, 0, stream>>>(qkv, kvT, attn);
  gemm256<1024, false><<<512, 512, 0, stream>>>(attn, wproj_t, proj_b, d_out, 1024, 64);
}

// Round 12
// 409.485 us; speedup vs baseline: 1.4800x; 1.0296x over previous
//
#include <hip/hip_runtime.h>
#include <stdint.h>

#define B_ 8
#define N_ 4096
#define C_ 1024
#define H_ 16
#define M_ (B_*N_)          // 32768 rows
#define BH_ (B_*H_)         // 128

typedef unsigned short u16;
typedef unsigned int   u32;
typedef __bf16 bf16x8 __attribute__((ext_vector_type(8)));
typedef float  f32x4  __attribute__((ext_vector_type(4)));

// ---------- helpers ----------
__device__ __forceinline__ u16 f2bf(float f) {
  union { float f; u32 u; } x; x.f = f;
  u32 r = x.u + 0x7fffu + ((x.u >> 16) & 1u);   // RNE
  return (u16)(r >> 16);
}
__device__ __forceinline__ float bf2f(u16 b) {
  union { u32 u; float f; } x; x.u = ((u32)b) << 16;
  return x.f;
}
__device__ __forceinline__ void gload16(const void* g, void* l) {
  __builtin_amdgcn_global_load_lds(
      (const __attribute__((address_space(1))) void*)g,
      (__attribute__((address_space(3))) void*)l,
      16, 0, 0);
}
__device__ __forceinline__ void unpack8(uint4 r, float* f) {
  const u32 w[4] = {r.x, r.y, r.z, r.w};
#pragma unroll
  for (int i = 0; i < 4; ++i) {
    f[2*i]   = bf2f((u16)(w[i] & 0xffffu));
    f[2*i+1] = bf2f((u16)(w[i] >> 16));
  }
}
__device__ __forceinline__ uint4 pack8(const float* f) {
  uint4 r; u32* w = (u32*)&r;
#pragma unroll
  for (int i = 0; i < 4; ++i)
    w[i] = (u32)f2bf(f[2*i]) | ((u32)f2bf(f[2*i+1]) << 16);
  return r;
}
__device__ __forceinline__ bf16x8 packbf8(const float* f) {
  uint4 p = pack8(f);
  return *reinterpret_cast<bf16x8*>(&p);
}

// ---------- 1) cast x fp32 -> bf16 ----------
__global__ void cast_f32_bf16(const float* __restrict__ in, u16* __restrict__ out, int n4) {
  int i = blockIdx.x * blockDim.x + threadIdx.x;
  const int stride = gridDim.x * blockDim.x;
  for (; i < n4; i += stride) {
    float4 v = reinterpret_cast<const float4*>(in)[i];
    u32 lo = (u32)f2bf(v.x) | ((u32)f2bf(v.y) << 16);
    u32 hi = (u32)f2bf(v.z) | ((u32)f2bf(v.w) << 16);
    uint2 o; o.x = lo; o.y = hi;
    reinterpret_cast<uint2*>(out)[i] = o;
  }
}

// ---------- 2) transpose + cast weights: [R][Cc] fp32 -> [Cc][R] bf16 ----------
__global__ void transpose_cast(const float* __restrict__ in, u16* __restrict__ out,
                               int R, int Cc) {
  __shared__ float t[32][33];
  const int bx = blockIdx.x * 32;
  const int by = blockIdx.y * 32;
  const int tx = threadIdx.x & 31;
  const int ty = threadIdx.x >> 5;
#pragma unroll
  for (int j = 0; j < 4; ++j) {
    const int r = by + ty + j * 8;
    t[ty + j * 8][tx] = in[(size_t)r * Cc + bx + tx];
  }
  __syncthreads();
#pragma unroll
  for (int j = 0; j < 4; ++j) {
    const int c = bx + ty + j * 8;
    out[(size_t)c * R + by + tx] = f2bf(t[tx][ty + j * 8]);
  }
}

// ---------- 3) 256x256 8-wave GEMM — R3 structure, phases merged 4->2 -------
// PhA: reads afA+bf0+bf1 (16); stage t+1 h1 pair; BAR; lgkm0; 32 MFMA
//      (quadrants (0,0),(0,1)); BAR.
// PhB: reads afB (8); stage t+2 h0 pair + GATE vmcnt(4); BAR; lgkm0; 32 MFMA
//      (quadrants (1,1),(1,0)); BAR.
// vmcnt ledger (items = half-stages x2): gate leaves exactly the 4 items of
// the t+2 h0 pair; retires t+1 h1 pair -> every read formally gated (as R3).
template <int NC, bool OUT_BF16>
__global__ __launch_bounds__(512) void gemm256(const u16* __restrict__ A,
                                               const u16* __restrict__ Bt,
                                               const float* __restrict__ bias,
                                               void* __restrict__ outp,
                                               int K, int cpx) {
  __shared__ __align__(16) u16 As[2][256][64];   // 64 KB
  __shared__ __align__(16) u16 Bs[2][256][64];   // 64 KB
  const int tid  = threadIdx.x;
  const int lane = tid & 63;
  const int w    = tid >> 6;
  const int wm   = (w >> 2) & 1;
  const int wn   = w & 3;
  const int l15  = lane & 15;
  const int lk   = lane >> 4;

  const int bid = blockIdx.x;
  const int wg  = (bid & 7) * cpx + (bid >> 3);
  // col fastest (mod 4), then row-tile, then col-group (L2-friendly, R11)
  const int col = ((wg >> 9) << 2) | (wg & 3);
  const size_t brow = (size_t)((wg >> 2) & 127) * 256;
  const size_t bcol = (size_t)col * 256;

  const int KT = K >> 6;
  f32x4 acc[2][2][4][2] = {};   // [mh][nh][mf][nf]

  auto stage = [&](const u16* __restrict__ src, size_t rowbase, int kt,
                   u16* lds_tile, int h) {
#pragma unroll
    for (int is = 0; is < 2; ++is) {
      const int lin   = is * 8192 + tid * 16;
      const int row   = lin >> 7;
      const int chunk = ((lin >> 4) & 7) ^ (row & 7);
      gload16(src + (rowbase + (size_t)(h * 128 + row)) * K + kt * 64 + chunk * 8,
              (char*)lds_tile + h * 16384 + lin);
    }
  };
  auto fragA = [&](const u16* tb, int mh, int mf, int kc) -> bf16x8 {
    const int row   = mh * 128 + wm * 64 + mf * 16 + l15;
    const int chunk = ((kc << 2) | lk) ^ (row & 7);
    return *reinterpret_cast<const bf16x8*>((const char*)tb + row * 128 + chunk * 16);
  };
  auto fragB = [&](const u16* tb, int nh, int nf, int kc) -> bf16x8 {
    const int row   = nh * 128 + wn * 32 + nf * 16 + l15;
    const int chunk = ((kc << 2) | lk) ^ (row & 7);
    return *reinterpret_cast<const bf16x8*>((const char*)tb + row * 128 + chunk * 16);
  };
  auto quad = [&](bf16x8 (&af)[4][2], bf16x8 (&bf)[2][2], f32x4 (&ac)[4][2]) {
#pragma unroll
    for (int mf = 0; mf < 4; ++mf)
#pragma unroll
      for (int nf = 0; nf < 2; ++nf)
#pragma unroll
        for (int kc = 0; kc < 2; ++kc)
          ac[mf][nf] = __builtin_amdgcn_mfma_f32_16x16x32_bf16(
              af[mf][kc], bf[nf][kc], ac[mf][nf], 0, 0, 0);
  };

  // prologue: tile0 fully + tile1 Ah0/Bh0 (12 items); vmcnt(4) -> tile0 done
  stage(A,  brow, 0, &As[0][0][0], 0);
  stage(Bt, bcol, 0, &Bs[0][0][0], 0);
  stage(A,  brow, 0, &As[0][0][0], 1);
  stage(Bt, bcol, 0, &Bs[0][0][0], 1);
  stage(A,  brow, 1, &As[1][0][0], 0);
  stage(Bt, bcol, 1, &Bs[1][0][0], 0);
  asm volatile("s_waitcnt vmcnt(4)" ::: "memory");
  __builtin_amdgcn_s_barrier();

  for (int t = 0; t < KT; ++t) {
    const u16* curA = &As[t & 1][0][0];
    const u16* curB = &Bs[t & 1][0][0];
    u16* nA  = &As[(t + 1) & 1][0][0];
    u16* nB  = &Bs[(t + 1) & 1][0][0];
    u16* n2A = &As[t & 1][0][0];
    u16* n2B = &Bs[t & 1][0][0];
    const bool s1 = (t + 1) < KT;
    const bool s2 = (t + 2) < KT;

    bf16x8 afA[4][2], afB[4][2], bf0[2][2], bf1[2][2];

    // ===== PhA: quadrants (0,0) + (0,1) =====
#pragma unroll
    for (int mf = 0; mf < 4; ++mf)
#pragma unroll
      for (int kc = 0; kc < 2; ++kc) afA[mf][kc] = fragA(curA, 0, mf, kc);
#pragma unroll
    for (int nf = 0; nf < 2; ++nf)
#pragma unroll
      for (int kc = 0; kc < 2; ++kc) bf0[nf][kc] = fragB(curB, 0, nf, kc);
#pragma unroll
    for (int nf = 0; nf < 2; ++nf)
#pragma unroll
      for (int kc = 0; kc < 2; ++kc) bf1[nf][kc] = fragB(curB, 1, nf, kc);
    if (s1) {
      stage(A,  brow, t + 1, nA, 1);
      stage(Bt, bcol, t + 1, nB, 1);
    }
    __builtin_amdgcn_s_barrier();
    asm volatile("s_waitcnt lgkmcnt(0)" ::: "memory");
    __builtin_amdgcn_s_setprio(1);
    quad(afA, bf0, acc[0][0]);
    quad(afA, bf1, acc[0][1]);
    __builtin_amdgcn_s_setprio(0);
    __builtin_amdgcn_s_barrier();

    // ===== PhB: quadrants (1,1) + (1,0) =====
#pragma unroll
    for (int mf = 0; mf < 4; ++mf)
#pragma unroll
      for (int kc = 0; kc < 2; ++kc) afB[mf][kc] = fragA(curA, 1, mf, kc);
    if (s2) {
      stage(A,  brow, t + 2, n2A, 0);
      stage(Bt, bcol, t + 2, n2B, 0);
      asm volatile("s_waitcnt vmcnt(4)" ::: "memory");
    } else {
      asm volatile("s_waitcnt vmcnt(0)" ::: "memory");
    }
    __builtin_amdgcn_s_barrier();
    asm volatile("s_waitcnt lgkmcnt(0)" ::: "memory");
    __builtin_amdgcn_s_setprio(1);
    quad(afB, bf1, acc[1][1]);
    quad(afB, bf0, acc[1][0]);
    __builtin_amdgcn_s_setprio(0);
    __builtin_amdgcn_s_barrier();
  }

  // epilogue: C/D layout col=lane&15, row=(lane>>4)*4+reg
#pragma unroll
  for (int mh = 0; mh < 2; ++mh)
#pragma unroll
  for (int nh = 0; nh < 2; ++nh)
#pragma unroll
  for (int mf = 0; mf < 4; ++mf)
#pragma unroll
  for (int nf = 0; nf < 2; ++nf) {
    const size_t ocol = bcol + nh * 128 + wn * 32 + nf * 16 + l15;
    const float bv = bias[ocol];
    const size_t row0 = brow + mh * 128 + wm * 64 + mf * 16 + lk * 4;
#pragma unroll
    for (int r = 0; r < 4; ++r) {
      const float v = acc[mh][nh][mf][nf][r] + bv;
      if constexpr (OUT_BF16)
        ((u16*)outp)[(row0 + r) * NC + ocol] = f2bf(v);
      else
        ((float*)outp)[(row0 + r) * NC + ocol] = v;
    }
  }
}

// ---------- 4) kv_fused: part[sp][bh][e][d] = sum_n v[n][e]*k_norm[n][d] ----
__global__ __launch_bounds__(256) void kv_fused(const u16* __restrict__ qkv,
                                                float* __restrict__ part) {
  const int bh = blockIdx.x, sp = blockIdx.y;
  const int b = bh >> 4, h = bh & 15;
  const int tid  = threadIdx.x;
  const int lane = tid & 63;
  const int w    = tid >> 6;
  const int wm   = w >> 1, wn = w & 1;
  const int l15  = lane & 15;
  const int lk   = lane >> 4;

  __shared__ float Ks[64 * 65];
  __shared__ float Vs[64 * 65];

  f32x4 acc[2][2] = {};
  const size_t nbase = (size_t)b * N_ + (size_t)sp * 512;

  for (int ch = 0; ch < 8; ++ch) {
    __syncthreads();
#pragma unroll
    for (int it = 0; it < 2; ++it) {
      const int idx = it * 256 + tid;
      const int r = idx >> 3, c8 = idx & 7;
      const size_t rowoff = (nbase + (size_t)(ch * 64 + r)) * 3072 + h * 64 + c8 * 8;
      uint4 kraw = *reinterpret_cast<const uint4*>(qkv + rowoff + 1024);
      float kf[8]; unpack8(kraw, kf);
      float ss = 0.f;
#pragma unroll
      for (int j = 0; j < 8; ++j) ss += kf[j] * kf[j];
      ss += __shfl_xor(ss, 1); ss += __shfl_xor(ss, 2); ss += __shfl_xor(ss, 4);
      const float sc = 1.f / fmaxf(sqrtf(ss), 1e-12f);
#pragma unroll
      for (int j = 0; j < 8; ++j) Ks[r * 65 + c8 * 8 + j] = kf[j] * sc;
      uint4 vraw = *reinterpret_cast<const uint4*>(qkv + rowoff + 2048);
      float vf[8]; unpack8(vraw, vf);
#pragma unroll
      for (int j = 0; j < 8; ++j) Vs[r * 65 + c8 * 8 + j] = vf[j];
    }
    __syncthreads();

    bf16x8 fa[2][2], fb[2][2];
#pragma unroll
    for (int mf = 0; mf < 2; ++mf)
#pragma unroll
      for (int kc = 0; kc < 2; ++kc) {
        const int e = wm * 32 + mf * 16 + l15;
        float tmp[8];
#pragma unroll
        for (int j = 0; j < 8; ++j) tmp[j] = Vs[(kc * 32 + lk * 8 + j) * 65 + e];
        fa[mf][kc] = packbf8(tmp);
      }
#pragma unroll
    for (int nf = 0; nf < 2; ++nf)
#pragma unroll
      for (int kc = 0; kc < 2; ++kc) {
        const int d = wn * 32 + nf * 16 + l15;
        float tmp[8];
#pragma unroll
        for (int j = 0; j < 8; ++j) tmp[j] = Ks[(kc * 32 + lk * 8 + j) * 65 + d];
        fb[nf][kc] = packbf8(tmp);
      }
#pragma unroll
    for (int mf = 0; mf < 2; ++mf)
#pragma unroll
      for (int nf = 0; nf < 2; ++nf)
#pragma unroll
        for (int kc = 0; kc < 2; ++kc)
          acc[mf][nf] = __builtin_amdgcn_mfma_f32_16x16x32_bf16(
              fa[mf][kc], fb[nf][kc], acc[mf][nf], 0, 0, 0);
  }

  float* base = part + ((size_t)sp * BH_ + bh) * 4096;
#pragma unroll
  for (int mf = 0; mf < 2; ++mf)
#pragma unroll
    for (int nf = 0; nf < 2; ++nf)
#pragma unroll
      for (int r = 0; r < 4; ++r) {
        const int e = wm * 32 + mf * 16 + lk * 4 + r;
        const int d = wn * 32 + nf * 16 + l15;
        base[e * 64 + d] = acc[mf][nf][r];
      }
}

// ---------- 5) reduce 8 kv partials -> kvT bf16 ----------
__global__ void kv_reduce8(const float* __restrict__ part, u16* __restrict__ kvT) {
  const int i4 = (blockIdx.x * 256 + threadIdx.x) * 4;
  float4 s = *reinterpret_cast<const float4*>(part + i4);
#pragma unroll
  for (int sp = 1; sp < 8; ++sp) {
    float4 p = *reinterpret_cast<const float4*>(part + (size_t)sp * 524288 + i4);
    s.x += p.x; s.y += p.y; s.z += p.z; s.w += p.w;
  }
  u32 lo = (u32)f2bf(s.x) | ((u32)f2bf(s.y) << 16);
  u32 hi = (u32)f2bf(s.z) | ((u32)f2bf(s.w) << 16);
  uint2 o; o.x = lo; o.y = hi;
  *reinterpret_cast<uint2*>(kvT + i4) = o;
}

// ---------- 6) attn_gemm: attn = (q @ kv) / ||q||, norm fused in-kernel ------
__global__ void attn_gemm(const u16* __restrict__ qkv, const u16* __restrict__ kvT,
                          u16* __restrict__ attn) {
  const int bh = blockIdx.x, nt = blockIdx.y;
  const int b = bh >> 4, h = bh & 15;
  const int n0 = nt * 128;
  __shared__ __align__(16) u16 Qs[128 * 64];
  __shared__ __align__(16) u16 Ks[64 * 64];
  __shared__ float qsl[128];
  const int tid  = threadIdx.x;
  const int lane = tid & 63;
  const int wm   = tid >> 6;
  const int l15  = lane & 15;
  const int lk   = lane >> 4;

#pragma unroll
  for (int is = 0; is < 4; ++is) {
    const int lin   = is * 4096 + tid * 16;
    const int row   = lin >> 7;
    const int chunk = ((lin >> 4) & 7) ^ (row & 7);
    gload16(qkv + ((size_t)(b * N_ + n0 + row)) * 3072 + h * 64 + chunk * 8,
            (char*)Qs + lin);
  }
#pragma unroll
  for (int is = 0; is < 2; ++is) {
    const int lin   = is * 4096 + tid * 16;
    const int row   = lin >> 7;
    const int chunk = ((lin >> 4) & 7) ^ (row & 7);
    gload16(kvT + (size_t)bh * 4096 + row * 64 + chunk * 8, (char*)Ks + lin);
  }
  __syncthreads();

  if (tid < 128) {
    float ss = 0.f;
#pragma unroll
    for (int c = 0; c < 8; ++c) {
      const int ch = (c + tid) & 7;
      uint4 raw = *reinterpret_cast<const uint4*>((const char*)Qs + tid * 128 + ch * 16);
      float f[8]; unpack8(raw, f);
#pragma unroll
      for (int j = 0; j < 8; ++j) ss += f[j] * f[j];
    }
    qsl[tid] = 1.f / fmaxf(sqrtf(ss), 1e-12f);
  }
  __syncthreads();

  bf16x8 fq[2][2], fk[4][2];
#pragma unroll
  for (int mf = 0; mf < 2; ++mf)
#pragma unroll
    for (int kc = 0; kc < 2; ++kc) {
      const int row = wm * 32 + mf * 16 + l15;
      const int chunk = ((kc << 2) | lk) ^ (row & 7);
      fq[mf][kc] = *reinterpret_cast<const bf16x8*>((const char*)Qs + row * 128 + chunk * 16);
    }
#pragma unroll
  for (int nf = 0; nf < 4; ++nf)
#pragma unroll
    for (int kc = 0; kc < 2; ++kc) {
      const int row = nf * 16 + l15;
      const int chunk = ((kc << 2) | lk) ^ (row & 7);
      fk[nf][kc] = *reinterpret_cast<const bf16x8*>((const char*)Ks + row * 128 + chunk * 16);
    }
  f32x4 acc[2][4] = {};
#pragma unroll
  for (int mf = 0; mf < 2; ++mf)
#pragma unroll
    for (int nf = 0; nf < 4; ++nf)
#pragma unroll
      for (int kc = 0; kc < 2; ++kc)
        acc[mf][nf] = __builtin_amdgcn_mfma_f32_16x16x32_bf16(
            fq[mf][kc], fk[nf][kc], acc[mf][nf], 0, 0, 0);

#pragma unroll
  for (int mf = 0; mf < 2; ++mf)
#pragma unroll
    for (int r = 0; r < 4; ++r) {
      const int rloc = wm * 32 + mf * 16 + lk * 4 + r;
      const size_t row = (size_t)(b * N_ + n0 + rloc);
      const float sc = qsl[rloc];
#pragma unroll
      for (int nf = 0; nf < 4; ++nf)
        attn[row * 1024 + h * 64 + nf * 16 + l15] = f2bf(acc[mf][nf][r] * sc);
    }
}

// ---------- workspace layout (bytes) ----------
#define WS_XB     0ull            // bf16 xb [32768][1024] (dead after QKV gemm)
#define WS_QKV    67108864ull     // bf16 [32768][3072] (q stays raw)
#define WS_VT     268435456ull    // part f32 [8][128][4096]=16MB, THEN attn bf16 64MB
#define WS_WQKV   335544320ull    // bf16 [3072][1024]
#define WS_WPROJ  341835776ull    // bf16 [1024][1024]
#define WS_KVT    360710144ull    // bf16 [128][64][64] = 1MB

extern "C" void kernel_launch(void* const* d_in, const int* in_sizes, int n_in,
                              void* d_out, int out_size, void* d_ws, size_t ws_size,
                              hipStream_t stream) {
  const float* x      = (const float*)d_in[0];
  const float* qkv_w  = (const float*)d_in[1];
  const float* qkv_b  = (const float*)d_in[2];
  const float* proj_w = (const float*)d_in[3];
  const float* proj_b = (const float*)d_in[4];

  char* ws = (char*)d_ws;
  u16*   xb      = (u16*)(ws + WS_XB);
  u16*   qkv     = (u16*)(ws + WS_QKV);
  float* part    = (float*)(ws + WS_VT);
  u16*   attn    = (u16*)(ws + WS_VT);
  u16*   wqkv_t  = (u16*)(ws + WS_WQKV);
  u16*   wproj_t = (u16*)(ws + WS_WPROJ);
  u16*   kvT     = (u16*)(ws + WS_KVT);

  cast_f32_bf16<<<2048, 256, 0, stream>>>(x, xb, (M_ * C_) / 4);
  transpose_cast<<<dim3(96, 32), 256, 0, stream>>>(qkv_w, wqkv_t, 1024, 3072);
  transpose_cast<<<dim3(32, 32), 256, 0, stream>>>(proj_w, wproj_t, 1024, 1024);
  gemm256<3072, true><<<1536, 512, 0, stream>>>(xb, wqkv_t, qkv_b, qkv, 1024, 192);
  kv_fused<<<dim3(128, 8), 256, 0, stream>>>(qkv, part);
  kv_reduce8<<<512, 256, 0, stream>>>(part, kvT);
  attn_gemm<<<dim3(128, 32), 256, 0, stream>>>(qkv, kvT, attn);
  gemm256<1024, false><<<512, 512, 0, stream>>>(attn, wproj_t, proj_b, d_out, 1024, 64);
}